// Round 1
// baseline (13562.070 us; speedup 1.0000x reference)
//
#include <hip/hip_runtime.h>
#include <stdint.h>
#include <cstdio>

typedef unsigned short u16;
typedef __attribute__((ext_vector_type(8))) __bf16 bf16x8;
typedef __attribute__((ext_vector_type(4))) float f32x4;

#define AGENT __HIP_MEMORY_SCOPE_AGENT

__device__ __forceinline__ float bf2f(u16 u) {
  unsigned int x = ((unsigned int)u) << 16;
  return __builtin_bit_cast(float, x);
}
__device__ __forceinline__ u16 f2bf(float f) {
  unsigned int x = __builtin_bit_cast(unsigned int, f);
  unsigned int r = (x + 0x7fffu + ((x >> 16) & 1u)) >> 16;
  return (u16)r;
}
__device__ __forceinline__ float sigm(float x) { return 1.f / (1.f + __expf(-x)); }
__device__ __forceinline__ float tanh_f(float x) { return 1.f - 2.f / (__expf(2.f * x) + 1.f); }

// ---------- fp32 -> bf16 convert (x) ----------
__global__ __launch_bounds__(256) void k_cvt(const float* __restrict__ in, u16* __restrict__ out, int n4) {
  int i = blockIdx.x * 256 + threadIdx.x;
  if (i >= n4) return;
  float4 f = ((const float4*)in)[i];
  ushort4 o;
  o.x = f2bf(f.x); o.y = f2bf(f.y); o.z = f2bf(f.z); o.w = f2bf(f.w);
  ((ushort4*)out)[i] = o;
}

// ---------- pack Wx [768][3072] -> B-fragment order [nt=192][kt=24][lane=64][j=8] ----------
__global__ __launch_bounds__(256) void k_pack_wx(const float* __restrict__ Wx, u16* __restrict__ Bp) {
  int idx = blockIdx.x * 256 + threadIdx.x;
  if (idx >= 2359296) return;
  int j = idx & 7;
  int l = (idx >> 3) & 63;
  int t = idx >> 9;          // nt*24 + kt
  int kt = t % 24, nt = t / 24;
  int k = kt * 32 + (l >> 4) * 8 + j;
  int n = nt * 16 + (l & 15);
  Bp[idx] = f2bf(Wx[(size_t)k * 3072 + n]);
}

// ---------- pack Wh -> per-WG slices [w=32][nt=6][kt=24][lane=64][j=8] ----------
// WG w owns units u in [w*24, w*24+24); packed col c = q*24 + u_local (q = gate 0..3)
__global__ __launch_bounds__(256) void k_pack_wh(const float* __restrict__ Wh, u16* __restrict__ Wp) {
  int idx = blockIdx.x * 256 + threadIdx.x;
  if (idx >= 2359296) return;
  int j = idx & 7;
  int l = (idx >> 3) & 63;
  int t = idx >> 9;          // w*144 + nt*24 + kt
  int kt = t % 24;
  int tmp = t / 24;          // w*6 + nt
  int nt = tmp % 6, w = tmp / 6;
  int k = kt * 32 + (l >> 4) * 8 + j;
  int c = nt * 16 + (l & 15);          // 0..95
  int q = c / 24, u = c - q * 24;
  int gcol = q * 768 + w * 24 + u;
  Wp[idx] = f2bf(Wh[(size_t)k * 3072 + gcol]);
}

// ---------- GEMM: C[16384][3072] bf16 = A[16384][768] bf16 @ Bp(packed) ----------
__global__ __launch_bounds__(256, 2) void k_gemm(const u16* __restrict__ A, const u16* __restrict__ Bp,
                                                 u16* __restrict__ C) {
  const int bid = blockIdx.x;
  const int bm = bid & 127, bn = bid >> 7;   // 128 x 24
  const int tid = threadIdx.x, lane = tid & 63, wv = tid >> 6;
  const int wm = wv >> 1, wn = wv & 1;
  const int row0 = bm * 128 + wm * 64;
  const int col0 = bn * 128 + wn * 64;
  const int rlo = lane & 15, rhi = lane >> 4;
  f32x4 acc[4][4] = {};
  const u16* Ab = A + (size_t)(row0 + rlo) * 768 + rhi * 8;
  const u16* Bb = Bp + ((size_t)(bn * 8 + wn * 4) * 24 * 64 + lane) * 8;
#pragma unroll 2
  for (int kt = 0; kt < 24; ++kt) {
    bf16x8 a[4], b[4];
#pragma unroll
    for (int i = 0; i < 4; ++i) a[i] = *(const bf16x8*)(Ab + (size_t)i * 16 * 768 + kt * 32);
#pragma unroll
    for (int j = 0; j < 4; ++j) b[j] = *(const bf16x8*)(Bb + (size_t)j * 24 * 64 * 8 + (size_t)kt * 64 * 8);
#pragma unroll
    for (int i = 0; i < 4; ++i)
#pragma unroll
      for (int j = 0; j < 4; ++j)
        acc[i][j] = __builtin_amdgcn_mfma_f32_16x16x32_bf16(a[i], b[j], acc[i][j], 0, 0, 0);
  }
#pragma unroll
  for (int i = 0; i < 4; ++i)
#pragma unroll
    for (int j = 0; j < 4; ++j)
#pragma unroll
      for (int r = 0; r < 4; ++r) {
        int row = row0 + i * 16 + rhi * 4 + r;
        int col = col0 + j * 16 + rlo;
        C[(size_t)row * 3072 + col] = f2bf(acc[i][j][r]);
      }
}

// ---------- persistent LSTM recurrence ----------
// grid = 256 WGs: group g = wid&7 (4 sequences), member w = wid>>3 (24 units)
__global__ __launch_bounds__(256, 1) void k_rec(
    const u16* __restrict__ xg,    // [16384][3072] bf16, m = seq*512 + t
    const u16* __restrict__ Whp,   // [32][6*24*64*8]
    const float* __restrict__ bias,
    u16* hbuf,                     // [8][2][4][768] bf16 (zeroed)
    int* flags,                    // [8][32] stride-32-int flags (zeroed)
    u16* __restrict__ hout_bf,     // layer 0 out (bf16) or null
    float* __restrict__ hout_f,    // layer 1 out (fp32) or null
    int layer) {
  __shared__ __align__(16) u16 ldsB[73728];   // 144 KB: per-WG Wh slice in frag order
  __shared__ float glds[4][96];               // gate staging / h staging

  const int wid = blockIdx.x, g = wid & 7, w = wid >> 3;
  const int tid = threadIdx.x, lane = tid & 63, wv = tid >> 6;

  { // stage Wh slice
    const int4* s4 = (const int4*)(Whp + (size_t)w * 73728);
    int4* d4 = (int4*)ldsB;
    for (int i = tid; i < 9216; i += 256) d4[i] = s4[i];
  }

  int nt0 = wv * 2, ntn = 2;
  if (wv >= 2) { nt0 = wv + 2; ntn = 1; }   // waves: {0,1},{2,3},{4},{5}

  const bool cellt = tid < 96;
  const int u = tid % 24, s = tid / 24;
  const int seq = g * 4 + (cellt ? s : 0);
  float bv0 = 0, bv1 = 0, bv2 = 0, bv3 = 0, xv0 = 0, xv1 = 0, xv2 = 0, xv3 = 0;
  int gc0 = 0, gc1 = 0, gc2 = 0, gc3 = 0;
  if (cellt) {
    int col = w * 24 + u;
    gc0 = col; gc1 = 768 + col; gc2 = 1536 + col; gc3 = 2304 + col;
    bv0 = bias[gc0]; bv1 = bias[gc1]; bv2 = bias[gc2]; bv3 = bias[gc3];
    const u16* xr = xg + (size_t)seq * 512 * 3072;
    xv0 = bf2f(xr[gc0]); xv1 = bf2f(xr[gc1]); xv2 = bf2f(xr[gc2]); xv3 = bf2f(xr[gc3]);
  }
  float cst = 0.f;
  const int sl = (lane & 15) < 4 ? (lane & 15) : 3;   // clamp pad rows (garbage ignored)
  int guard = 0;

  __syncthreads();

  for (int t = 0; t < 512; ++t) {
    // prefetch next step's xg (hides HBM latency under MFMA+barriers)
    float nx0 = 0, nx1 = 0, nx2 = 0, nx3 = 0;
    if (cellt && t + 1 < 512) {
      const u16* xr = xg + ((size_t)seq * 512 + t + 1) * 3072;
      nx0 = bf2f(xr[gc0]); nx1 = bf2f(xr[gc1]); nx2 = bf2f(xr[gc2]); nx3 = bf2f(xr[gc3]);
    }
    // ---- MFMA: gates[4 seq][96 cols] += h_{t-1}[4][768] @ WhSlice ----
    const u16* hrow = hbuf + ((size_t)(g * 2 + ((t + 1) & 1)) * 4 + sl) * 768 + (lane >> 4) * 8;
    f32x4 acc0 = {0, 0, 0, 0}, acc1 = {0, 0, 0, 0};
#pragma unroll
    for (int kt = 0; kt < 24; ++kt) {
      bf16x8 af = *(const bf16x8*)(hrow + kt * 32);
      bf16x8 b0 = *(const bf16x8*)(ldsB + ((size_t)(nt0 * 24 + kt) * 64 + lane) * 8);
      acc0 = __builtin_amdgcn_mfma_f32_16x16x32_bf16(af, b0, acc0, 0, 0, 0);
      if (ntn == 2) {
        bf16x8 b1 = *(const bf16x8*)(ldsB + ((size_t)((nt0 + 1) * 24 + kt) * 64 + lane) * 8);
        acc1 = __builtin_amdgcn_mfma_f32_16x16x32_bf16(af, b1, acc1, 0, 0, 0);
      }
    }
    // D layout: col = lane&15, row(seq) = (lane>>4)*4 + reg -> valid rows live in lanes 0..15
    if (lane < 16) {
#pragma unroll
      for (int r = 0; r < 4; ++r) glds[r][nt0 * 16 + lane] = acc0[r];
      if (ntn == 2) {
#pragma unroll
        for (int r = 0; r < 4; ++r) glds[r][(nt0 + 1) * 16 + lane] = acc1[r];
      }
    }
    __syncthreads();   // B1: gates ready
    if (cellt) {
      float p0 = xv0 + glds[s][u] + bv0;
      float p1 = xv1 + glds[s][24 + u] + bv1;
      float p2 = xv2 + glds[s][48 + u] + bv2;
      float p3 = xv3 + glds[s][72 + u] + bv3;
      float ig = sigm(p0), fg = sigm(p1), gg = tanh_f(p2), og = sigm(p3);
      cst = fg * cst + ig * gg;
      float h = og * tanh_f(cst);
      glds[s][u] = h;   // own-slot reuse (read-before-write, 1:1 slot ownership)
      size_t o = ((size_t)seq * 512 + t) * 768 + w * 24 + u;
      if (layer == 0) hout_bf[o] = f2bf(h); else hout_f[o] = h;
    }
    xv0 = nx0; xv1 = nx1; xv2 = nx2; xv3 = nx3;
    __syncthreads();   // B2a: h values staged in LDS
    // broadcast h as packed 4B agent-scope stores (write-through to coherence point)
    if (tid < 48) {
      int ss = tid / 12, e = tid % 12;
      unsigned int val = (unsigned int)f2bf(glds[ss][e * 2]) | ((unsigned int)f2bf(glds[ss][e * 2 + 1]) << 16);
      int* dst = (int*)(hbuf + ((size_t)(g * 2 + (t & 1)) * 4 + ss) * 768) + w * 12 + e;
      __hip_atomic_store(dst, (int)val, __ATOMIC_RELAXED, AGENT);
    }
    __syncthreads();   // B2b: broadcast stores drained (vmcnt(0) before barrier)
    if (tid == 0) {
      __hip_atomic_store(&flags[(g * 32 + w) * 32], t + 1, __ATOMIC_RELAXED, AGENT);
    }
    // poll all 32 member flags (lane-parallel), bounded to avoid hangs
    int fv;
    do {
      fv = __hip_atomic_load(&flags[(g * 32 + (lane & 31)) * 32], __ATOMIC_RELAXED, AGENT);
      if (++guard > (1 << 22)) break;
    } while (!__all(fv >= t + 1));
    __builtin_amdgcn_fence(__ATOMIC_ACQUIRE, "agent");  // invalidate stale copies before reading hbuf
  }
}

// ---------- LayerNorm (in-place safe) ----------
__global__ __launch_bounds__(256) void k_ln(const float* __restrict__ in, const float* __restrict__ sc,
                                            const float* __restrict__ bi, float* __restrict__ out) {
  const int row = blockIdx.x, tid = threadIdx.x;
  const float* x = in + (size_t)row * 768;
  float v0 = x[tid], v1 = x[tid + 256], v2 = x[tid + 512];
  float s = v0 + v1 + v2;
  float s2 = v0 * v0 + v1 * v1 + v2 * v2;
#pragma unroll
  for (int off = 32; off >= 1; off >>= 1) {
    s += __shfl_xor(s, off);
    s2 += __shfl_xor(s2, off);
  }
  __shared__ float red[8];
  const int wv = tid >> 6;
  if ((tid & 63) == 0) { red[wv] = s; red[4 + wv] = s2; }
  __syncthreads();
  s = red[0] + red[1] + red[2] + red[3];
  s2 = red[4] + red[5] + red[6] + red[7];
  float mean = s * (1.f / 768.f);
  float var = s2 * (1.f / 768.f) - mean * mean;
  float rs = rsqrtf(var + 1e-6f);
  float* o = out + (size_t)row * 768;
  o[tid] = (v0 - mean) * rs * sc[tid] + bi[tid];
  o[tid + 256] = (v1 - mean) * rs * sc[tid + 256] + bi[tid + 256];
  o[tid + 512] = (v2 - mean) * rs * sc[tid + 512] + bi[tid + 512];
}

extern "C" void kernel_launch(void* const* d_in, const int* in_sizes, int n_in,
                              void* d_out, int out_size, void* d_ws, size_t ws_size,
                              hipStream_t stream) {
  const float* x   = (const float*)d_in[0];
  const float* Wx0 = (const float*)d_in[1];
  const float* Wh0 = (const float*)d_in[2];
  const float* b0  = (const float*)d_in[3];
  const float* Wx1 = (const float*)d_in[4];
  const float* Wh1 = (const float*)d_in[5];
  const float* b1  = (const float*)d_in[6];
  const float* lns = (const float*)d_in[7];
  const float* lnb = (const float*)d_in[8];
  float* out = (float*)d_out;

  char* p = (char*)d_ws;
  auto alloc = [&](size_t bytes) {
    char* r = p;
    p += (bytes + 255) & ~(size_t)255;
    return r;
  };
  u16* xg    = (u16*)alloc(16384ull * 3072 * 2);
  u16* xbf   = (u16*)alloc(16384ull * 768 * 2);
  u16* h0bf  = (u16*)alloc(16384ull * 768 * 2);
  u16* Wxp0  = (u16*)alloc(2359296ull * 2);
  u16* Wxp1  = (u16*)alloc(2359296ull * 2);
  u16* Whp0  = (u16*)alloc(2359296ull * 2);
  u16* Whp1  = (u16*)alloc(2359296ull * 2);
  char* sync0 = alloc(98304 * 2 + 32768 * 2);   // hbuf0, hbuf1, flags0, flags1
  u16* hbuf0 = (u16*)sync0;
  u16* hbuf1 = (u16*)(sync0 + 98304);
  int* flags0 = (int*)(sync0 + 98304 * 2);
  int* flags1 = (int*)(sync0 + 98304 * 2 + 32768);

  if ((size_t)(p - (char*)d_ws) > ws_size) {
    fprintf(stderr, "kernel_launch: ws too small: need %zu have %zu\n",
            (size_t)(p - (char*)d_ws), ws_size);
    return;
  }

  hipMemsetAsync(sync0, 0, 98304 * 2 + 32768 * 2, stream);
  k_cvt<<<12288, 256, 0, stream>>>(x, xbf, 3145728);
  k_pack_wx<<<9216, 256, 0, stream>>>(Wx0, Wxp0);
  k_pack_wx<<<9216, 256, 0, stream>>>(Wx1, Wxp1);
  k_pack_wh<<<9216, 256, 0, stream>>>(Wh0, Whp0);
  k_pack_wh<<<9216, 256, 0, stream>>>(Wh1, Whp1);

  k_gemm<<<3072, 256, 0, stream>>>(xbf, Wxp0, xg);
  k_rec<<<256, 256, 0, stream>>>(xg, Whp0, b0, hbuf0, flags0, h0bf, nullptr, 0);
  k_gemm<<<3072, 256, 0, stream>>>(h0bf, Wxp1, xg);
  k_rec<<<256, 256, 0, stream>>>(xg, Whp1, b1, hbuf1, flags1, nullptr, (float*)d_out, 1);
  k_ln<<<16384, 256, 0, stream>>>((const float*)d_out, lns, lnb, out);
}

// Round 2
// 4009.490 us; speedup vs baseline: 3.3825x; 3.3825x over previous
//
#include <hip/hip_runtime.h>
#include <stdint.h>
#include <cstdio>

typedef unsigned short u16;
typedef __attribute__((ext_vector_type(8))) __bf16 bf16x8;
typedef __attribute__((ext_vector_type(4))) float f32x4;
typedef __attribute__((ext_vector_type(4))) int i32x4;

#define AGENT __HIP_MEMORY_SCOPE_AGENT

__device__ __forceinline__ float bf2f(u16 u) {
  unsigned int x = ((unsigned int)u) << 16;
  return __builtin_bit_cast(float, x);
}
__device__ __forceinline__ u16 f2bf(float f) {
  unsigned int x = __builtin_bit_cast(unsigned int, f);
  unsigned int r = (x + 0x7fffu + ((x >> 16) & 1u)) >> 16;
  return (u16)r;
}
__device__ __forceinline__ float sigm(float x) { return 1.f / (1.f + __expf(-x)); }
__device__ __forceinline__ float tanh_f(float x) { return 1.f - 2.f / (__expf(2.f * x) + 1.f); }

// cache-bypassing 16B load (misses L1/L2, reads at the coherence point)
__device__ __forceinline__ i32x4 load16_cc(const void* p) {
  i32x4 r;
  asm volatile("global_load_dwordx4 %0, %1, off sc0 sc1" : "=v"(r) : "v"(p) : "memory");
  return r;
}

// ---------- fp32 -> bf16 convert (x) ----------
__global__ __launch_bounds__(256) void k_cvt(const float* __restrict__ in, u16* __restrict__ out, int n4) {
  int i = blockIdx.x * 256 + threadIdx.x;
  if (i >= n4) return;
  float4 f = ((const float4*)in)[i];
  ushort4 o;
  o.x = f2bf(f.x); o.y = f2bf(f.y); o.z = f2bf(f.z); o.w = f2bf(f.w);
  ((ushort4*)out)[i] = o;
}

// ---------- pack Wx [768][3072] -> B-fragment order [nt=192][kt=24][lane=64][j=8] ----------
__global__ __launch_bounds__(256) void k_pack_wx(const float* __restrict__ Wx, u16* __restrict__ Bp) {
  int idx = blockIdx.x * 256 + threadIdx.x;
  if (idx >= 2359296) return;
  int j = idx & 7;
  int l = (idx >> 3) & 63;
  int t = idx >> 9;          // nt*24 + kt
  int kt = t % 24, nt = t / 24;
  int k = kt * 32 + (l >> 4) * 8 + j;
  int n = nt * 16 + (l & 15);
  Bp[idx] = f2bf(Wx[(size_t)k * 3072 + n]);
}

// ---------- pack Wh -> per-WG slices [w=32][nt=6][kt=24][lane=64][j=8] ----------
__global__ __launch_bounds__(256) void k_pack_wh(const float* __restrict__ Wh, u16* __restrict__ Wp) {
  int idx = blockIdx.x * 256 + threadIdx.x;
  if (idx >= 2359296) return;
  int j = idx & 7;
  int l = (idx >> 3) & 63;
  int t = idx >> 9;          // w*144 + nt*24 + kt
  int kt = t % 24;
  int tmp = t / 24;          // w*6 + nt
  int nt = tmp % 6, w = tmp / 6;
  int k = kt * 32 + (l >> 4) * 8 + j;
  int c = nt * 16 + (l & 15);          // 0..95
  int q = c / 24, u = c - q * 24;
  int gcol = q * 768 + w * 24 + u;
  Wp[idx] = f2bf(Wh[(size_t)k * 3072 + gcol]);
}

// ---------- GEMM: C[16384][3072] bf16 = A[16384][768] bf16 @ Bp(packed) ----------
__global__ __launch_bounds__(256, 2) void k_gemm(const u16* __restrict__ A, const u16* __restrict__ Bp,
                                                 u16* __restrict__ C) {
  const int bid = blockIdx.x;
  const int bm = bid & 127, bn = bid >> 7;   // 128 x 24
  const int tid = threadIdx.x, lane = tid & 63, wv = tid >> 6;
  const int wm = wv >> 1, wn = wv & 1;
  const int row0 = bm * 128 + wm * 64;
  const int col0 = bn * 128 + wn * 64;
  const int rlo = lane & 15, rhi = lane >> 4;
  f32x4 acc[4][4] = {};
  const u16* Ab = A + (size_t)(row0 + rlo) * 768 + rhi * 8;
  const u16* Bb = Bp + ((size_t)(bn * 8 + wn * 4) * 24 * 64 + lane) * 8;
#pragma unroll 2
  for (int kt = 0; kt < 24; ++kt) {
    bf16x8 a[4], b[4];
#pragma unroll
    for (int i = 0; i < 4; ++i) a[i] = *(const bf16x8*)(Ab + (size_t)i * 16 * 768 + kt * 32);
#pragma unroll
    for (int j = 0; j < 4; ++j) b[j] = *(const bf16x8*)(Bb + (size_t)j * 24 * 64 * 8 + (size_t)kt * 64 * 8);
#pragma unroll
    for (int i = 0; i < 4; ++i)
#pragma unroll
      for (int j = 0; j < 4; ++j)
        acc[i][j] = __builtin_amdgcn_mfma_f32_16x16x32_bf16(a[i], b[j], acc[i][j], 0, 0, 0);
  }
#pragma unroll
  for (int i = 0; i < 4; ++i)
#pragma unroll
    for (int j = 0; j < 4; ++j)
#pragma unroll
      for (int r = 0; r < 4; ++r) {
        int row = row0 + i * 16 + rhi * 4 + r;
        int col = col0 + j * 16 + rlo;
        C[(size_t)row * 3072 + col] = f2bf(acc[i][j][r]);
      }
}

// ---------- persistent LSTM recurrence ----------
// grid = 256 WGs: group g = wid&7 (4 sequences), member w = wid>>3 (24 units)
// Protocol per step t:
//   waves 2,3: poll flags>=t -> sc0sc1-load h_{t-1} (buf[t&1]) -> hlds
//   B3; all waves MFMA gates -> glds; B1
//   waves 0,1 (tid<96): cell math -> packed h store (buf[(t+1)&1], atomic agent)
//                       -> wave-level vmcnt(0) -> flag=t+1 -> hout + xg prefetch
__global__ __launch_bounds__(256, 1) void k_rec(
    const u16* __restrict__ xg,    // [16384][3072] bf16, m = seq*512 + t
    const u16* __restrict__ Whp,   // [32][6*24*64*8]
    const float* __restrict__ bias,
    u16* hbuf,                     // [8][2][4][768] bf16 (zeroed)
    int* flags,                    // [8][64] flags, 64B apart (zeroed)
    u16* __restrict__ hout_bf,     // layer 0 out (bf16) or null
    float* __restrict__ hout_f,    // layer 1 out (fp32) or null
    int layer) {
  __shared__ __align__(16) u16 ldsB[73728];    // 144 KB Wh slice (frag order)
  __shared__ __align__(16) int hlds[4 * 388];  // h_{t-1} [4 rows][384 dw], +4 dw row pad
  __shared__ float glds[4][96];                // gate staging

  const int wid = blockIdx.x, g = wid & 7, w = wid >> 3;
  const int tid = threadIdx.x, lane = tid & 63, wv = tid >> 6;

  { // stage Wh slice
    const int4* s4 = (const int4*)(Whp + (size_t)w * 73728);
    int4* d4 = (int4*)ldsB;
    for (int i = tid; i < 9216; i += 256) d4[i] = s4[i];
  }

  // wave -> nt tiles: wv0->{0}, wv1->{1}, wv2->{2,3}, wv3->{4,5}
  const int nt0 = (wv < 2) ? wv : (wv * 2 - 2);
  const int ntn = (wv < 2) ? 1 : 2;

  const bool cellt = tid < 96;
  const int u = tid % 24, s = tid / 24;
  const int seq = g * 4 + (cellt ? s : 0);
  float bv0 = 0, bv1 = 0, bv2 = 0, bv3 = 0, xv0 = 0, xv1 = 0, xv2 = 0, xv3 = 0;
  int gc0 = 0, gc1 = 0, gc2 = 0, gc3 = 0;
  if (cellt) {
    int col = w * 24 + u;
    gc0 = col; gc1 = 768 + col; gc2 = 1536 + col; gc3 = 2304 + col;
    bv0 = bias[gc0]; bv1 = bias[gc1]; bv2 = bias[gc2]; bv3 = bias[gc3];
    const u16* xr = xg + (size_t)seq * 512 * 3072;
    xv0 = bf2f(xr[gc0]); xv1 = bf2f(xr[gc1]); xv2 = bf2f(xr[gc2]); xv3 = bf2f(xr[gc3]);
  }
  float cst = 0.f;
  const int sl = (lane & 15) < 4 ? (lane & 15) : 3;  // A-frag row (clamped pad rows)
  const int acol = (lane >> 4) * 4;                  // A-frag dword col base
  int guard = 0;

  __syncthreads();  // ldsB staged

  for (int t = 0; t < 512; ++t) {
    if (wv >= 2) {
      if (t > 0) {  // poll: h_{t-1} published by all 64 producer waves
        int fv;
        do {
          fv = __hip_atomic_load(&flags[(g * 64 + lane) * 16], __ATOMIC_RELAXED, AGENT);
          if (++guard > (1 << 22)) break;
        } while (!__all(fv >= t));
      }
      // stage h_{t-1} -> hlds with cache-bypassing loads (128 threads x 3 x 16B = 6KB)
      const char* src = (const char*)(hbuf + (size_t)(g * 2 + (t & 1)) * 4 * 768);
      const int c0 = tid - 128;  // 0..127
      i32x4 v0 = load16_cc(src + (size_t)c0 * 16);
      i32x4 v1 = load16_cc(src + (size_t)(c0 + 128) * 16);
      i32x4 v2 = load16_cc(src + (size_t)(c0 + 256) * 16);
      asm volatile("s_waitcnt vmcnt(0)" ::: "memory");
      {
        int c = c0;      int r = c / 96; *(i32x4*)&hlds[r * 388 + (c - r * 96) * 4] = v0;
        c = c0 + 128;    r = c / 96;     *(i32x4*)&hlds[r * 388 + (c - r * 96) * 4] = v1;
        c = c0 + 256;    r = c / 96;     *(i32x4*)&hlds[r * 388 + (c - r * 96) * 4] = v2;
      }
    }
    __syncthreads();  // B3: hlds ready

    // ---- MFMA: gates[4 seq][96 cols] = h_{t-1}[4][768] @ WhSlice, kt-parity split ----
    f32x4 a0 = {0, 0, 0, 0}, a1 = {0, 0, 0, 0}, a2 = {0, 0, 0, 0}, a3 = {0, 0, 0, 0};
#pragma unroll
    for (int kt = 0; kt < 24; kt += 2) {
      bf16x8 afe = *(const bf16x8*)(hlds + sl * 388 + kt * 16 + acol);
      bf16x8 afo = *(const bf16x8*)(hlds + sl * 388 + (kt + 1) * 16 + acol);
      bf16x8 b0e = *(const bf16x8*)(ldsB + ((size_t)(nt0 * 24 + kt) * 64 + lane) * 8);
      bf16x8 b0o = *(const bf16x8*)(ldsB + ((size_t)(nt0 * 24 + kt + 1) * 64 + lane) * 8);
      a0 = __builtin_amdgcn_mfma_f32_16x16x32_bf16(afe, b0e, a0, 0, 0, 0);
      a1 = __builtin_amdgcn_mfma_f32_16x16x32_bf16(afo, b0o, a1, 0, 0, 0);
      if (ntn == 2) {
        bf16x8 b1e = *(const bf16x8*)(ldsB + ((size_t)((nt0 + 1) * 24 + kt) * 64 + lane) * 8);
        bf16x8 b1o = *(const bf16x8*)(ldsB + ((size_t)((nt0 + 1) * 24 + kt + 1) * 64 + lane) * 8);
        a2 = __builtin_amdgcn_mfma_f32_16x16x32_bf16(afe, b1e, a2, 0, 0, 0);
        a3 = __builtin_amdgcn_mfma_f32_16x16x32_bf16(afo, b1o, a3, 0, 0, 0);
      }
    }
    a0 += a1; a2 += a3;
    // D layout: col = lane&15, row(seq) = (lane>>4)*4 + reg -> rows 0-3 live in lanes 0-15
    if (lane < 16) {
#pragma unroll
      for (int r = 0; r < 4; ++r) glds[r][nt0 * 16 + lane] = a0[r];
      if (ntn == 2) {
#pragma unroll
        for (int r = 0; r < 4; ++r) glds[r][(nt0 + 1) * 16 + lane] = a2[r];
      }
    }
    __syncthreads();  // B1: gates ready

    if (cellt) {
      float p0 = xv0 + glds[s][u] + bv0;
      float p1 = xv1 + glds[s][24 + u] + bv1;
      float p2 = xv2 + glds[s][48 + u] + bv2;
      float p3 = xv3 + glds[s][72 + u] + bv3;
      float ig = sigm(p0), fg = sigm(p1), gg = tanh_f(p2), og = sigm(p3);
      cst = fg * cst + ig * gg;
      float h = og * tanh_f(cst);
      float hhi = __shfl_down(h, 1);  // pair partner (u+1, same wave)
      if ((u & 1) == 0) {
        unsigned int val = (unsigned int)f2bf(h) | ((unsigned int)f2bf(hhi) << 16);
        int* dst = (int*)hbuf + ((size_t)(g * 2 + ((t + 1) & 1)) * 4 + s) * 384 + ((w * 24 + u) >> 1);
        __hip_atomic_store(dst, (int)val, __ATOMIC_RELAXED, AGENT);
      }
      asm volatile("s_waitcnt vmcnt(0)" ::: "memory");  // wave-level drain: h at coherence point
      if (lane == 0) {
        __hip_atomic_store(&flags[(g * 64 + w * 2 + wv) * 16], t + 1, __ATOMIC_RELAXED, AGENT);
      }
      // off the critical path: output store + next-step xg prefetch
      size_t o = ((size_t)seq * 512 + t) * 768 + w * 24 + u;
      if (layer == 0) hout_bf[o] = f2bf(h); else hout_f[o] = h;
      if (t + 1 < 512) {
        const u16* xr = xg + ((size_t)seq * 512 + t + 1) * 3072;
        xv0 = bf2f(xr[gc0]); xv1 = bf2f(xr[gc1]); xv2 = bf2f(xr[gc2]); xv3 = bf2f(xr[gc3]);
      }
    }
  }
}

// ---------- LayerNorm (in-place safe) ----------
__global__ __launch_bounds__(256) void k_ln(const float* __restrict__ in, const float* __restrict__ sc,
                                            const float* __restrict__ bi, float* __restrict__ out) {
  const int row = blockIdx.x, tid = threadIdx.x;
  const float* x = in + (size_t)row * 768;
  float v0 = x[tid], v1 = x[tid + 256], v2 = x[tid + 512];
  float s = v0 + v1 + v2;
  float s2 = v0 * v0 + v1 * v1 + v2 * v2;
#pragma unroll
  for (int off = 32; off >= 1; off >>= 1) {
    s += __shfl_xor(s, off);
    s2 += __shfl_xor(s2, off);
  }
  __shared__ float red[8];
  const int wv = tid >> 6;
  if ((tid & 63) == 0) { red[wv] = s; red[4 + wv] = s2; }
  __syncthreads();
  s = red[0] + red[1] + red[2] + red[3];
  s2 = red[4] + red[5] + red[6] + red[7];
  float mean = s * (1.f / 768.f);
  float var = s2 * (1.f / 768.f) - mean * mean;
  float rs = rsqrtf(var + 1e-6f);
  float* o = out + (size_t)row * 768;
  o[tid] = (v0 - mean) * rs * sc[tid] + bi[tid];
  o[tid + 256] = (v1 - mean) * rs * sc[tid + 256] + bi[tid + 256];
  o[tid + 512] = (v2 - mean) * rs * sc[tid + 512] + bi[tid + 512];
}

extern "C" void kernel_launch(void* const* d_in, const int* in_sizes, int n_in,
                              void* d_out, int out_size, void* d_ws, size_t ws_size,
                              hipStream_t stream) {
  const float* x   = (const float*)d_in[0];
  const float* Wx0 = (const float*)d_in[1];
  const float* Wh0 = (const float*)d_in[2];
  const float* b0  = (const float*)d_in[3];
  const float* Wx1 = (const float*)d_in[4];
  const float* Wh1 = (const float*)d_in[5];
  const float* b1  = (const float*)d_in[6];
  const float* lns = (const float*)d_in[7];
  const float* lnb = (const float*)d_in[8];
  float* out = (float*)d_out;

  char* p = (char*)d_ws;
  auto alloc = [&](size_t bytes) {
    char* r = p;
    p += (bytes + 255) & ~(size_t)255;
    return r;
  };
  u16* xg    = (u16*)alloc(16384ull * 3072 * 2);
  u16* xbf   = (u16*)alloc(16384ull * 768 * 2);
  u16* h0bf  = (u16*)alloc(16384ull * 768 * 2);
  u16* Wxp0  = (u16*)alloc(2359296ull * 2);
  u16* Wxp1  = (u16*)alloc(2359296ull * 2);
  u16* Whp0  = (u16*)alloc(2359296ull * 2);
  u16* Whp1  = (u16*)alloc(2359296ull * 2);
  char* sync0 = alloc(98304 * 2 + 32768 * 2);   // hbuf0, hbuf1, flags0, flags1
  u16* hbuf0 = (u16*)sync0;
  u16* hbuf1 = (u16*)(sync0 + 98304);
  int* flags0 = (int*)(sync0 + 98304 * 2);
  int* flags1 = (int*)(sync0 + 98304 * 2 + 32768);

  if ((size_t)(p - (char*)d_ws) > ws_size) {
    fprintf(stderr, "kernel_launch: ws too small: need %zu have %zu\n",
            (size_t)(p - (char*)d_ws), ws_size);
    return;
  }

  hipMemsetAsync(sync0, 0, 98304 * 2 + 32768 * 2, stream);
  k_cvt<<<12288, 256, 0, stream>>>(x, xbf, 3145728);
  k_pack_wx<<<9216, 256, 0, stream>>>(Wx0, Wxp0);
  k_pack_wx<<<9216, 256, 0, stream>>>(Wx1, Wxp1);
  k_pack_wh<<<9216, 256, 0, stream>>>(Wh0, Whp0);
  k_pack_wh<<<9216, 256, 0, stream>>>(Wh1, Whp1);

  k_gemm<<<3072, 256, 0, stream>>>(xbf, Wxp0, xg);
  k_rec<<<256, 256, 0, stream>>>(xg, Whp0, b0, hbuf0, flags0, h0bf, nullptr, 0);
  k_gemm<<<3072, 256, 0, stream>>>(h0bf, Wxp1, xg);
  k_rec<<<256, 256, 0, stream>>>(xg, Whp1, b1, hbuf1, flags1, nullptr, (float*)d_out, 1);
  k_ln<<<16384, 256, 0, stream>>>((const float*)d_out, lns, lnb, out);
}

// Round 3
// 2878.788 us; speedup vs baseline: 4.7110x; 1.3928x over previous
//
#include <hip/hip_runtime.h>
#include <stdint.h>
#include <cstdio>

typedef unsigned short u16;
typedef __attribute__((ext_vector_type(8))) __bf16 bf16x8;
typedef __attribute__((ext_vector_type(4))) float f32x4;
typedef __attribute__((ext_vector_type(4))) int i32x4;

#define AGENT __HIP_MEMORY_SCOPE_AGENT

__device__ __forceinline__ float bf2f(u16 u) {
  unsigned int x = ((unsigned int)u) << 16;
  return __builtin_bit_cast(float, x);
}
__device__ __forceinline__ u16 f2bf(float f) {
  unsigned int x = __builtin_bit_cast(unsigned int, f);
  unsigned int r = (x + 0x7fffu + ((x >> 16) & 1u)) >> 16;
  return (u16)r;
}
__device__ __forceinline__ float sigm(float x) { return 1.f / (1.f + __expf(-x)); }
__device__ __forceinline__ float tanh_f(float x) { return 1.f - 2.f / (__expf(2.f * x) + 1.f); }

// ---------- fp32 -> bf16 convert (x) ----------
__global__ __launch_bounds__(256) void k_cvt(const float* __restrict__ in, u16* __restrict__ out, int n4) {
  int i = blockIdx.x * 256 + threadIdx.x;
  if (i >= n4) return;
  float4 f = ((const float4*)in)[i];
  ushort4 o;
  o.x = f2bf(f.x); o.y = f2bf(f.y); o.z = f2bf(f.z); o.w = f2bf(f.w);
  ((ushort4*)out)[i] = o;
}

// ---------- pack Wx [768][3072] -> B-fragment order [nt=192][kt=24][lane=64][j=8] ----------
__global__ __launch_bounds__(256) void k_pack_wx(const float* __restrict__ Wx, u16* __restrict__ Bp) {
  int idx = blockIdx.x * 256 + threadIdx.x;
  if (idx >= 2359296) return;
  int j = idx & 7;
  int l = (idx >> 3) & 63;
  int t = idx >> 9;          // nt*24 + kt
  int kt = t % 24, nt = t / 24;
  int k = kt * 32 + (l >> 4) * 8 + j;
  int n = nt * 16 + (l & 15);
  Bp[idx] = f2bf(Wx[(size_t)k * 3072 + n]);
}

// ---------- pack Wh -> per-WG slices [w=32][nt=6][kt=24][lane=64][j=8] ----------
__global__ __launch_bounds__(256) void k_pack_wh(const float* __restrict__ Wh, u16* __restrict__ Wp) {
  int idx = blockIdx.x * 256 + threadIdx.x;
  if (idx >= 2359296) return;
  int j = idx & 7;
  int l = (idx >> 3) & 63;
  int t = idx >> 9;          // w*144 + nt*24 + kt
  int kt = t % 24;
  int tmp = t / 24;          // w*6 + nt
  int nt = tmp % 6, w = tmp / 6;
  int k = kt * 32 + (l >> 4) * 8 + j;
  int c = nt * 16 + (l & 15);          // 0..95
  int q = c / 24, u = c - q * 24;
  int gcol = q * 768 + w * 24 + u;
  Wp[idx] = f2bf(Wh[(size_t)k * 3072 + gcol]);
}

// ---------- GEMM: C[16384][3072] bf16 = A[16384][768] bf16 @ Bp(packed) ----------
__global__ __launch_bounds__(256, 2) void k_gemm(const u16* __restrict__ A, const u16* __restrict__ Bp,
                                                 u16* __restrict__ C) {
  const int bid = blockIdx.x;
  const int bm = bid & 127, bn = bid >> 7;   // 128 x 24
  const int tid = threadIdx.x, lane = tid & 63, wv = tid >> 6;
  const int wm = wv >> 1, wn = wv & 1;
  const int row0 = bm * 128 + wm * 64;
  const int col0 = bn * 128 + wn * 64;
  const int rlo = lane & 15, rhi = lane >> 4;
  f32x4 acc[4][4] = {};
  const u16* Ab = A + (size_t)(row0 + rlo) * 768 + rhi * 8;
  const u16* Bb = Bp + ((size_t)(bn * 8 + wn * 4) * 24 * 64 + lane) * 8;
#pragma unroll 2
  for (int kt = 0; kt < 24; ++kt) {
    bf16x8 a[4], b[4];
#pragma unroll
    for (int i = 0; i < 4; ++i) a[i] = *(const bf16x8*)(Ab + (size_t)i * 16 * 768 + kt * 32);
#pragma unroll
    for (int j = 0; j < 4; ++j) b[j] = *(const bf16x8*)(Bb + (size_t)j * 24 * 64 * 8 + (size_t)kt * 64 * 8);
#pragma unroll
    for (int i = 0; i < 4; ++i)
#pragma unroll
      for (int j = 0; j < 4; ++j)
        acc[i][j] = __builtin_amdgcn_mfma_f32_16x16x32_bf16(a[i], b[j], acc[i][j], 0, 0, 0);
  }
#pragma unroll
  for (int i = 0; i < 4; ++i)
#pragma unroll
    for (int j = 0; j < 4; ++j)
#pragma unroll
      for (int r = 0; r < 4; ++r) {
        int row = row0 + i * 16 + rhi * 4 + r;
        int col = col0 + j * 16 + rlo;
        C[(size_t)row * 3072 + col] = f2bf(acc[i][j][r]);
      }
}

// ---------- persistent LSTM recurrence ----------
// grid = 256 WGs x 384 threads (6 waves). group g = wid&7 (4 seqs), member w = wid>>3 (24 units).
// Wh slice lives in VGPRs: wave wv owns nt tile = wv (16 gate cols x 768 K = 24 bf16x8 frags/lane).
// Sync: h published as dword (bf16_h<<16 | tag), tag = t+1; consumers speculative-load + tag-check.
// Double buffer by t parity. No flags, no producer-side waits.
__global__ __launch_bounds__(384) void k_rec(
    const u16* __restrict__ xg,    // [16384][3072] bf16, m = seq*512 + t
    const u16* __restrict__ Whp,   // [32][6*24*64*8] packed bf16
    const float* __restrict__ bias,
    int* hbuf,                     // [8 groups][2][3072] tagged dwords (zeroed)
    u16* __restrict__ hout_bf,     // layer 0 out (bf16) or null
    float* __restrict__ hout_f,    // layer 1 out (fp32) or null
    int layer) {
  __shared__ __align__(16) int hlds[4 * 400];  // h_{t-1}[4 seq][768] bf16, rows padded to 400 dw
  __shared__ float glds[4][96];                // gate staging
  __shared__ char ldspad[84 * 1024];           // forces 1 WG/CU (co-residency guarantee)

  const int wid = blockIdx.x, g = wid & 7, w = wid >> 3;
  const int tid = threadIdx.x, lane = tid & 63, wv = tid >> 6;
  if (layer == 0x7fffffff) ((volatile char*)ldspad)[tid] = 1;  // keep pad allocated

  // ---- Wh fragments -> VGPRs (static indices; stays in registers) ----
  bf16x8 bregE[12], bregO[12];
  {
    const u16* bp = Whp + (((size_t)(w * 6 + wv) * 24) * 64 + lane) * 8;
#pragma unroll
    for (int kk = 0; kk < 12; ++kk) {
      bregE[kk] = *(const bf16x8*)(bp + (size_t)(2 * kk) * 512);
      bregO[kk] = *(const bf16x8*)(bp + (size_t)(2 * kk + 1) * 512);
    }
  }

  const bool cellt = tid < 96;
  const int u = tid % 24, s = tid / 24;
  const int seq = g * 4 + (cellt ? s : 0);
  float bv0 = 0, bv1 = 0, bv2 = 0, bv3 = 0, xv0 = 0, xv1 = 0, xv2 = 0, xv3 = 0;
  int gc0 = 0, gc1 = 0, gc2 = 0, gc3 = 0;
  if (cellt) {
    int col = w * 24 + u;
    gc0 = col; gc1 = 768 + col; gc2 = 1536 + col; gc3 = 2304 + col;
    bv0 = bias[gc0]; bv1 = bias[gc1]; bv2 = bias[gc2]; bv3 = bias[gc3];
    const u16* xr = xg + (size_t)seq * 512 * 3072;
    xv0 = bf2f(xr[gc0]); xv1 = bf2f(xr[gc1]); xv2 = bf2f(xr[gc2]); xv3 = bf2f(xr[gc3]);
  }
  float cst = 0.f;
  const int sl = (lane & 15) < 4 ? (lane & 15) : 3;      // A-frag row (pad rows clamped)
  const int abase = sl * 400 + (lane >> 4) * 4;          // A-frag dword base in hlds
  int guard = 0;

  __syncthreads();

  for (int t = 0; t < 512; ++t) {
    // ---- consumers (waves 2-5): speculative tagged load of h_{t-1} ----
    if (tid >= 128) {
      const int expect = t;  // tag stored by step t-1 producers (t=0: zeroed buffer)
      int* src = hbuf + (size_t)(g * 2 + (t & 1)) * 3072;
      const int c = tid - 128;  // 0..255, 3 chunks of 4 dwords each
      const int* p0 = src + 4 * c;
      const int* p1 = src + 4 * (c + 256);
      const int* p2 = src + 4 * (c + 512);
      if (t > 0) {  // cheap sentinel poll first (1 dword)
        int sv;
        do {
          asm volatile("global_load_dword %0, %1, off sc0 sc1\n\ts_waitcnt vmcnt(0)"
                       : "=&v"(sv) : "v"(p0) : "memory");
        } while ((sv & 0xffff) != expect && ++guard < (1 << 24));
      }
      i32x4 v0, v1, v2;
      for (;;) {
        asm volatile("global_load_dwordx4 %0, %3, off sc0 sc1\n\t"
                     "global_load_dwordx4 %1, %4, off sc0 sc1\n\t"
                     "global_load_dwordx4 %2, %5, off sc0 sc1\n\t"
                     "s_waitcnt vmcnt(0)"
                     : "=&v"(v0), "=&v"(v1), "=&v"(v2)
                     : "v"(p0), "v"(p1), "v"(p2)
                     : "memory");
        bool ok = true;
#pragma unroll
        for (int j = 0; j < 4; ++j)
          ok = ok && ((v0[j] & 0xffff) == expect) && ((v1[j] & 0xffff) == expect) &&
               ((v2[j] & 0xffff) == expect);
        if (ok || ++guard > (1 << 24)) break;
      }
      // pack tags out, stage bf16 pairs to hlds
      {
        int ch = c;
        int2 o;
        o.x = (int)(((unsigned)v0[0] >> 16) | ((unsigned)v0[1] & 0xffff0000u));
        o.y = (int)(((unsigned)v0[2] >> 16) | ((unsigned)v0[3] & 0xffff0000u));
        *(int2*)&hlds[(ch / 192) * 400 + (ch % 192) * 2] = o;
        ch = c + 256;
        o.x = (int)(((unsigned)v1[0] >> 16) | ((unsigned)v1[1] & 0xffff0000u));
        o.y = (int)(((unsigned)v1[2] >> 16) | ((unsigned)v1[3] & 0xffff0000u));
        *(int2*)&hlds[(ch / 192) * 400 + (ch % 192) * 2] = o;
        ch = c + 512;
        o.x = (int)(((unsigned)v2[0] >> 16) | ((unsigned)v2[1] & 0xffff0000u));
        o.y = (int)(((unsigned)v2[2] >> 16) | ((unsigned)v2[3] & 0xffff0000u));
        *(int2*)&hlds[(ch / 192) * 400 + (ch % 192) * 2] = o;
      }
    }
    __syncthreads();  // B3: hlds ready

    // ---- MFMA: gates[4][16 cols of tile wv] = h_{t-1} @ Wh(regs), 2 indep chains ----
    f32x4 a0 = {0, 0, 0, 0}, a1 = {0, 0, 0, 0};
#pragma unroll
    for (int kk = 0; kk < 12; ++kk) {
      bf16x8 afe = *(const bf16x8*)(hlds + abase + (2 * kk) * 16);
      bf16x8 afo = *(const bf16x8*)(hlds + abase + (2 * kk + 1) * 16);
      a0 = __builtin_amdgcn_mfma_f32_16x16x32_bf16(afe, bregE[kk], a0, 0, 0, 0);
      a1 = __builtin_amdgcn_mfma_f32_16x16x32_bf16(afo, bregO[kk], a1, 0, 0, 0);
    }
    a0 += a1;
    // D layout: col = lane&15, row = (lane>>4)*4 + reg -> rows 0-3 live in lanes 0-15
    if (lane < 16) {
#pragma unroll
      for (int r = 0; r < 4; ++r) glds[r][wv * 16 + lane] = a0[r];
    }
    __syncthreads();  // B1: gates ready

    if (cellt) {
      float p0 = xv0 + glds[s][u] + bv0;
      float p1 = xv1 + glds[s][24 + u] + bv1;
      float p2 = xv2 + glds[s][48 + u] + bv2;
      float p3 = xv3 + glds[s][72 + u] + bv3;
      float ig = sigm(p0), fg = sigm(p1), gg = tanh_f(p2), og = sigm(p3);
      cst = fg * cst + ig * gg;
      float h = og * tanh_f(cst);
      // publish tagged h (fire-and-forget; dword atomicity makes it self-validating)
      int* dst = hbuf + (size_t)(g * 2 + ((t + 1) & 1)) * 3072 + s * 768 + w * 24 + u;
      int val = (int)(((unsigned)f2bf(h) << 16) | (unsigned)(t + 1));
      __hip_atomic_store(dst, val, __ATOMIC_RELAXED, AGENT);
      // off the critical path: output store + next-step xg prefetch
      size_t o = ((size_t)seq * 512 + t) * 768 + w * 24 + u;
      if (layer == 0) hout_bf[o] = f2bf(h); else hout_f[o] = h;
      if (t + 1 < 512) {
        const u16* xr = xg + ((size_t)seq * 512 + t + 1) * 3072;
        xv0 = bf2f(xr[gc0]); xv1 = bf2f(xr[gc1]); xv2 = bf2f(xr[gc2]); xv3 = bf2f(xr[gc3]);
      }
    }
  }
}

// ---------- LayerNorm (in-place safe) ----------
__global__ __launch_bounds__(256) void k_ln(const float* __restrict__ in, const float* __restrict__ sc,
                                            const float* __restrict__ bi, float* __restrict__ out) {
  const int row = blockIdx.x, tid = threadIdx.x;
  const float* x = in + (size_t)row * 768;
  float v0 = x[tid], v1 = x[tid + 256], v2 = x[tid + 512];
  float s = v0 + v1 + v2;
  float s2 = v0 * v0 + v1 * v1 + v2 * v2;
#pragma unroll
  for (int off = 32; off >= 1; off >>= 1) {
    s += __shfl_xor(s, off);
    s2 += __shfl_xor(s2, off);
  }
  __shared__ float red[8];
  const int wv = tid >> 6;
  if ((tid & 63) == 0) { red[wv] = s; red[4 + wv] = s2; }
  __syncthreads();
  s = red[0] + red[1] + red[2] + red[3];
  s2 = red[4] + red[5] + red[6] + red[7];
  float mean = s * (1.f / 768.f);
  float var = s2 * (1.f / 768.f) - mean * mean;
  float rs = rsqrtf(var + 1e-6f);
  float* o = out + (size_t)row * 768;
  o[tid] = (v0 - mean) * rs * sc[tid] + bi[tid];
  o[tid + 256] = (v1 - mean) * rs * sc[tid + 256] + bi[tid + 256];
  o[tid + 512] = (v2 - mean) * rs * sc[tid + 512] + bi[tid + 512];
}

extern "C" void kernel_launch(void* const* d_in, const int* in_sizes, int n_in,
                              void* d_out, int out_size, void* d_ws, size_t ws_size,
                              hipStream_t stream) {
  const float* x   = (const float*)d_in[0];
  const float* Wx0 = (const float*)d_in[1];
  const float* Wh0 = (const float*)d_in[2];
  const float* b0  = (const float*)d_in[3];
  const float* Wx1 = (const float*)d_in[4];
  const float* Wh1 = (const float*)d_in[5];
  const float* b1  = (const float*)d_in[6];
  const float* lns = (const float*)d_in[7];
  const float* lnb = (const float*)d_in[8];
  float* out = (float*)d_out;

  char* p = (char*)d_ws;
  auto alloc = [&](size_t bytes) {
    char* r = p;
    p += (bytes + 255) & ~(size_t)255;
    return r;
  };
  u16* xg    = (u16*)alloc(16384ull * 3072 * 2);
  u16* xbf   = (u16*)alloc(16384ull * 768 * 2);
  u16* h0bf  = (u16*)alloc(16384ull * 768 * 2);
  u16* Wxp0  = (u16*)alloc(2359296ull * 2);
  u16* Wxp1  = (u16*)alloc(2359296ull * 2);
  u16* Whp0  = (u16*)alloc(2359296ull * 2);
  u16* Whp1  = (u16*)alloc(2359296ull * 2);
  char* sync0 = alloc(196608ull * 2);   // hbuf0, hbuf1 (tagged dwords)
  int* hbuf0 = (int*)sync0;
  int* hbuf1 = (int*)(sync0 + 196608);

  if ((size_t)(p - (char*)d_ws) > ws_size) {
    fprintf(stderr, "kernel_launch: ws too small: need %zu have %zu\n",
            (size_t)(p - (char*)d_ws), ws_size);
    return;
  }

  hipMemsetAsync(sync0, 0, 196608ull * 2, stream);
  k_cvt<<<12288, 256, 0, stream>>>(x, xbf, 3145728);
  k_pack_wx<<<9216, 256, 0, stream>>>(Wx0, Wxp0);
  k_pack_wx<<<9216, 256, 0, stream>>>(Wx1, Wxp1);
  k_pack_wh<<<9216, 256, 0, stream>>>(Wh0, Whp0);
  k_pack_wh<<<9216, 256, 0, stream>>>(Wh1, Whp1);

  k_gemm<<<3072, 256, 0, stream>>>(xbf, Wxp0, xg);
  k_rec<<<256, 384, 0, stream>>>(xg, Whp0, b0, hbuf0, h0bf, nullptr, 0);
  k_gemm<<<3072, 256, 0, stream>>>(h0bf, Wxp1, xg);
  k_rec<<<256, 384, 0, stream>>>(xg, Whp1, b1, hbuf1, nullptr, (float*)d_out, 1);
  k_ln<<<16384, 256, 0, stream>>>((const float*)d_out, lns, lnb, out);
}